// Round 7
// baseline (528.899 us; speedup 1.0000x reference)
//
#include <hip/hip_runtime.h>
#include <hip/hip_bf16.h>

#define M_TOK 16384   // B*S
#define DDIM  1024
#define NEXP  8
#define KP    (NEXP * DDIM)   // 8192 fused K

typedef __bf16 bf16x8  __attribute__((ext_vector_type(8)));
typedef float  floatx4 __attribute__((ext_vector_type(4)));
typedef float  floatx16 __attribute__((ext_vector_type(16)));

__device__ __forceinline__ void gload_lds16(const void* g, void* l) {
    __builtin_amdgcn_global_load_lds(
        (__attribute__((address_space(1))) void*)(void*)g,
        (__attribute__((address_space(3))) void*)l,
        16, 0, 0);
}

// ---------------------------------------------------------------------------
// Kernel 1: route logits + softmax + h->bf16.  LDS-free: W_route (32 KB) is
// read straight from global — coalesced, L1-resident after first touch
// (old LDS version had 8-way bank conflicts on every dot read).
// rw layout per token (8 floats): [0..6] = w_e/w_{e+1} ratios, [7] = w_7.
// ---------------------------------------------------------------------------
__global__ __launch_bounds__(256) void route_kernel(
    const float* __restrict__ h, const float* __restrict__ Wr,
    const float* __restrict__ br, __bf16* __restrict__ hbf,
    float* __restrict__ rw)
{
    const int tid = threadIdx.x;
    const int wave = tid >> 6, lane = tid & 63;
    const int m = blockIdx.x * 4 + wave;

    const float4* hrow = (const float4*)(h + (size_t)m * DDIM + lane * 16);
    float a[16];
    #pragma unroll
    for (int i = 0; i < 4; ++i) {
        float4 v = hrow[i];
        a[i*4+0] = v.x; a[i*4+1] = v.y; a[i*4+2] = v.z; a[i*4+3] = v.w;
    }
    bf16x8 o0, o1;
    #pragma unroll
    for (int i = 0; i < 8; ++i) { o0[i] = (__bf16)a[i]; o1[i] = (__bf16)a[8 + i]; }
    *(bf16x8*)(hbf + (size_t)m * DDIM + lane * 16)     = o0;
    *(bf16x8*)(hbf + (size_t)m * DDIM + lane * 16 + 8) = o1;

    float p[NEXP];
    #pragma unroll
    for (int e = 0; e < NEXP; ++e) {
        const float4* w4 = (const float4*)(Wr + e * DDIM + lane * 16);
        float s = 0.f;
        #pragma unroll
        for (int i = 0; i < 4; ++i) {
            float4 wv = w4[i];
            s += a[i*4+0]*wv.x + a[i*4+1]*wv.y + a[i*4+2]*wv.z + a[i*4+3]*wv.w;
        }
        p[e] = s;
    }
    #pragma unroll
    for (int e = 0; e < NEXP; ++e) {
        #pragma unroll
        for (int off = 32; off > 0; off >>= 1)
            p[e] += __shfl_xor(p[e], off, 64);
    }
    if (lane == 0) {
        float l[NEXP], mx = -1e30f;
        #pragma unroll
        for (int e = 0; e < NEXP; ++e) { l[e] = p[e] + br[e]; mx = fmaxf(mx, l[e]); }
        float s = 0.f;
        #pragma unroll
        for (int e = 0; e < NEXP; ++e) { l[e] = expf(l[e] - mx); s += l[e]; }
        float inv = 1.f / s;
        float w[NEXP];
        #pragma unroll
        for (int e = 0; e < NEXP; ++e) w[e] = fmaxf(l[e] * inv, 1e-20f);
        // slots 0..6 = w_e / w_{e+1}; slot 7 = w_7
        float o[NEXP];
        #pragma unroll
        for (int e = 0; e < NEXP - 1; ++e) o[e] = w[e] / w[e + 1];
        o[7] = w[7];
        float4 r0 = {o[0], o[1], o[2], o[3]};
        float4 r1 = {o[4], o[5], o[6], o[7]};
        *(float4*)(rw + (size_t)m * NEXP)     = r0;
        *(float4*)(rw + (size_t)m * NEXP + 4) = r1;
    }
}

// ---------------------------------------------------------------------------
// Kernel 2: W_edges [e][f][k] fp32 -> B'[f][e*1024+k] bf16
// ---------------------------------------------------------------------------
__global__ __launch_bounds__(256) void convw2_kernel(
    const float* __restrict__ src, __bf16* __restrict__ dst)
{
    size_t idx = ((size_t)blockIdx.x * 256 + threadIdx.x) * 16;
    int e = (int)(idx >> 20);
    int f = (int)(idx >> 10) & 1023;
    int k = (int)idx & 1023;
    const float4* s4 = (const float4*)(src + idx);
    float a[16];
    #pragma unroll
    for (int i = 0; i < 4; ++i) {
        float4 v = s4[i];
        a[i*4+0] = v.x; a[i*4+1] = v.y; a[i*4+2] = v.z; a[i*4+3] = v.w;
    }
    bf16x8 o0, o1;
    #pragma unroll
    for (int i = 0; i < 8; ++i) { o0[i] = (__bf16)a[i]; o1[i] = (__bf16)a[8 + i]; }
    __bf16* d = dst + (size_t)f * KP + (size_t)e * DDIM + k;
    *(bf16x8*)d       = o0;
    *(bf16x8*)(d + 8) = o1;
}

// ---------------------------------------------------------------------------
// Kernel 3: fused MoE GEMM, online expert rescaling, 32x32x16 bf16 MFMA.
// 128x128 block tile, BK=64, 4 waves (2x2), wave tile 64x64 = 2x2 frags of
// 32x32.  XOR-swizzled LDS (16B granularity, conflict-free).
// A/B frag: [row=lane&31][k=(lane>>5)*8+j]; C/D: col=lane&31,
// row=(reg&3)+8*(reg>>2)+4*(lane>>5)  (m74/m101-verified mapping).
// Boundary: facc *= rw_ratio (precomputed in route, broadcast LDS read).
// ---------------------------------------------------------------------------
__global__ __launch_bounds__(256, 3) void gemm_fused_kernel(
    const __bf16* __restrict__ hbf, const __bf16* __restrict__ Bp,
    const float* __restrict__ rw, const float* __restrict__ bias,
    float* __restrict__ outp)
{
    __shared__ __bf16 As[128 * 64];
    __shared__ __bf16 Bs[128 * 64];
    __shared__ float  rws[128 * NEXP];

    const int tid  = threadIdx.x;
    const int wave = tid >> 6, lane = tid & 63;
    const int half = lane >> 5, l32 = lane & 31;
    const int wm = wave & 1, wn = wave >> 1;
    const int m0 = blockIdx.y * 128, f0 = blockIdx.x * 128;

    {
        const float4* src = (const float4*)(rw + (size_t)m0 * NEXP);
        ((float4*)rws)[tid] = src[tid];
    }

    floatx16 facc[2][2];
    #pragma unroll
    for (int i = 0; i < 2; ++i)
        #pragma unroll
        for (int j = 0; j < 2; ++j)
            #pragma unroll
            for (int r = 0; r < 16; ++r) facc[i][j][r] = 0.f;

    // XOR-swizzled LDS read slots: slot = row*8 + ((grp ^ row)&7), grp = ks*2+half
    int aslot[4][2], bslot[4][2];
    #pragma unroll
    for (int ks = 0; ks < 4; ++ks) {
        #pragma unroll
        for (int b = 0; b < 2; ++b) {
            int ra = wm*64 + b*32 + l32;
            int rb = wn*64 + b*32 + l32;
            int grp = ks*2 + half;
            aslot[ks][b] = ra*8 + ((grp ^ ra) & 7);
            bslot[ks][b] = rb*8 + ((grp ^ rb) & 7);
        }
    }

    __syncthreads();  // rws visible

    for (int e = 0; e < NEXP; ++e) {
        if (e > 0) {
            // facc *= w_{e-1}/w_e  (slot e-1; broadcast read, 2 muls per row-reg)
            #pragma unroll
            for (int mb = 0; mb < 2; ++mb) {
                #pragma unroll
                for (int r = 0; r < 16; ++r) {
                    int lrow = wm*64 + mb*32 + (r & 3) + 8*(r >> 2) + 4*half;
                    float ratio = rws[lrow * NEXP + (e - 1)];
                    facc[mb][0][r] *= ratio;
                    facc[mb][1][r] *= ratio;
                }
            }
        }

        for (int k0 = 0; k0 < DDIM; k0 += 64) {
            __syncthreads();
            #pragma unroll
            for (int t = 0; t < 4; ++t) {
                int g   = t * 256 + tid;
                int row = g >> 3;
                int c   = ((g ^ row) & 7) * 8;   // swizzled column group
                gload_lds16(hbf + (size_t)(m0 + row) * DDIM + k0 + c,
                            (char*)As + g * 16);
                gload_lds16(Bp + (size_t)(f0 + row) * KP + e * DDIM + k0 + c,
                            (char*)Bs + g * 16);
            }
            __syncthreads();

            #pragma unroll
            for (int ks = 0; ks < 4; ++ks) {
                bf16x8 av[2], bv[2];
                #pragma unroll
                for (int mb = 0; mb < 2; ++mb)
                    av[mb] = *(const bf16x8*)&As[aslot[ks][mb] * 8];
                #pragma unroll
                for (int nb = 0; nb < 2; ++nb)
                    bv[nb] = *(const bf16x8*)&Bs[bslot[ks][nb] * 8];
                #pragma unroll
                for (int mb = 0; mb < 2; ++mb) {
                    #pragma unroll
                    for (int nb = 0; nb < 2; ++nb)
                        facc[mb][nb] = __builtin_amdgcn_mfma_f32_32x32x16_bf16(
                            av[mb], bv[nb], facc[mb][nb], 0, 0, 0);
                }
            }
        }
    }

    // epilogue: out = GELU(facc * w_7 + bias)
    int col[2]; float bval[2];
    #pragma unroll
    for (int nb = 0; nb < 2; ++nb) {
        col[nb] = f0 + wn*64 + nb*32 + l32;
        bval[nb] = bias[col[nb]];
    }
    #pragma unroll
    for (int mb = 0; mb < 2; ++mb) {
        #pragma unroll
        for (int r = 0; r < 16; ++r) {
            int lrow = wm*64 + mb*32 + (r & 3) + 8*(r >> 2) + 4*half;
            float w7 = rws[lrow * NEXP + 7];
            #pragma unroll
            for (int nb = 0; nb < 2; ++nb) {
                float x = facc[mb][nb][r] * w7 + bval[nb];
                float gel = 0.5f * x * (1.0f + erff(x * 0.70710678118f));
                outp[(size_t)(m0 + lrow) * DDIM + col[nb]] = gel;
            }
        }
    }
}

// ---------------------------------------------------------------------------
extern "C" void kernel_launch(void* const* d_in, const int* in_sizes, int n_in,
                              void* d_out, int out_size, void* d_ws, size_t ws_size,
                              hipStream_t stream) {
    const float* h    = (const float*)d_in[0];   // [4,4096,1024]
    const float* Wr   = (const float*)d_in[1];   // [8,1024]
    const float* br   = (const float*)d_in[2];   // [8]
    const float* We   = (const float*)d_in[3];   // [8,1024,1024]
    const float* bias = (const float*)d_in[4];   // [1024]
    float* outp = (float*)d_out;
    char* ws = (char*)d_ws;

    __bf16* hbf = (__bf16*)ws;                                   // 32 MiB
    __bf16* Bp  = (__bf16*)(ws + (size_t)M_TOK * DDIM * 2);      // 16 MiB
    float*  rwp = (float*)(ws + (size_t)M_TOK * DDIM * 2
                              + (size_t)NEXP * DDIM * DDIM * 2); // 512 KiB

    hipLaunchKernelGGL(route_kernel, dim3(M_TOK / 4), dim3(256), 0, stream,
                       h, Wr, br, hbf, rwp);
    hipLaunchKernelGGL(convw2_kernel, dim3((NEXP * DDIM * DDIM) / (256 * 16)),
                       dim3(256), 0, stream, We, Bp);
    hipLaunchKernelGGL(gemm_fused_kernel, dim3(DDIM / 128, M_TOK / 128),
                       dim3(256), 0, stream, hbf, Bp, rwp, bias, outp);
}